// Round 6
// baseline (4486.017 us; speedup 1.0000x reference)
//
#include <hip/hip_runtime.h>

// ---------------- problem constants ----------------
#define NB 256     // batch
#define NT 512     // seq len
#define NI 128     // input size
#define NH 512     // hidden
#define NO 128     // output size
#define NGRP 16    // batch groups
#define RPG 16     // rows (batch) per group
#define BPG 8      // blocks per group (each owns 64 cols)

typedef __attribute__((ext_vector_type(8))) __bf16 bf16x8;
typedef __attribute__((ext_vector_type(4))) float  f32x4;
typedef unsigned long long u64;

#define MFMA16(a,b,c) __builtin_amdgcn_mfma_f32_16x16x32_bf16((a),(b),(c),0,0,0)

// ---------------- LDS layout (R4-identical) ----------------
#define XSZ   (RPG*NI*2)           // 4096
#define HSZ   (RPG*NH*2)           // 16384
#define XOFF  0
#define H0OFF (2*XSZ)              // 8192
#define H1OFF (H0OFF + HSZ)        // 24576
#define SMEM_BYTES (H1OFF + HSZ)   // 40960

__device__ __forceinline__ float fast_tanh(float x){
  x = fminf(15.f, fmaxf(-15.f, x));
  float e = __expf(2.f * x);
  return 1.f - 2.f / (e + 1.f);
}

__device__ __forceinline__ bf16x8 cvt8(float4 a, float4 b){
  bf16x8 r;
  r[0]=(__bf16)a.x; r[1]=(__bf16)a.y; r[2]=(__bf16)a.z; r[3]=(__bf16)a.w;
  r[4]=(__bf16)b.x; r[5]=(__bf16)b.y; r[6]=(__bf16)b.z; r[7]=(__bf16)b.w;
  return r;
}

__device__ __forceinline__ bf16x8 loadWfrag(const float* __restrict__ W, int ldk, int row, int k0){
  const float4* p = (const float4*)(W + (size_t)row * ldk + k0);
  return cvt8(p[0], p[1]);
}

// proven slow medium: relaxed agent atomics (coherent at L3, any placement)
__device__ __forceinline__ void st_u64(u64* p, u64 v){
  __hip_atomic_store(p, v, __ATOMIC_RELAXED, __HIP_MEMORY_SCOPE_AGENT);
}
__device__ __forceinline__ u64 ld_u64(const u64* p){
  return __hip_atomic_load(p, __ATOMIC_RELAXED, __HIP_MEMORY_SCOPE_AGENT);
}
__device__ __forceinline__ void st_u32(unsigned* p, unsigned v){
  __hip_atomic_store(p, v, __ATOMIC_RELAXED, __HIP_MEMORY_SCOPE_AGENT);
}
__device__ __forceinline__ unsigned ld_u32(const unsigned* p){
  return __hip_atomic_load(p, __ATOMIC_RELAXED, __HIP_MEMORY_SCOPE_AGENT);
}

// fast medium (same-XCD only): whole-L1 invalidate, then plain loads hit shared L2
__device__ __forceinline__ void l1_inv(){
  asm volatile("buffer_inv" ::: "memory");
}

__device__ __forceinline__ u64 pack4bf(f32x4 v){
  union { __bf16 h[4]; u64 u; } un;
  un.h[0]=(__bf16)v[0]; un.h[1]=(__bf16)v[1]; un.h[2]=(__bf16)v[2]; un.h[3]=(__bf16)v[3];
  return un.u;
}

__global__ __launch_bounds__(256, 1)
void rnn_persistent(const float* __restrict__ x,
                    const float* __restrict__ hid,
                    const float* __restrict__ Wih0, const float* __restrict__ bih0,
                    const float* __restrict__ Whh0, const float* __restrict__ bhh0,
                    const float* __restrict__ Wih1, const float* __restrict__ bih1,
                    const float* __restrict__ Whh1, const float* __restrict__ bhh1,
                    const float* __restrict__ fcW,  const float* __restrict__ fcb,
                    float* __restrict__ out,
                    unsigned* __restrict__ xcc,     // 128 u32 (memset 0 each launch)
                    unsigned* __restrict__ flags,   // 16*64 u32 (memset 0 each launch)
                    __bf16* __restrict__ h0g, __bf16* __restrict__ h1g)
{
  __shared__ __align__(16) char smem[SMEM_BYTES];

  const int tid  = threadIdx.x;
  const int lane = tid & 63;
  const int wv   = tid >> 6;
  const int lr   = lane & 15;
  const int lq   = lane >> 4;

  const int bq  = blockIdx.x;
  const int j   = (bq >> 3) & 7;            // block-in-group: cols [j*64, j*64+64)
  const int g   = (bq & 7) + 8 * (bq >> 6); // group 0..15; members share blockIdx%8
  const int cb  = j * 64 + wv * 16;
  const int row0 = g * RPG;
  const int wid  = j * 4 + wv;              // wave id in group, 0..31

  // publish XCC id first; poll after weight loads (discovery latency hidden)
  unsigned myx;
  asm volatile("s_getreg_b32 %0, hwreg(HW_REG_XCC_ID)" : "=s"(myx));
  myx &= 0xfu;
  if (tid == 0) st_u32(xcc + bq, 0x5A00u | myx);

  // ---------------- weights -> registers (MFMA A operands) ----------------
  bf16x8 wih0[4], whh0[16], wih1[16], whh1[16];
#pragma unroll
  for (int kt = 0; kt < 4;  ++kt) wih0[kt] = loadWfrag(Wih0, NI, cb + lr, kt*32 + lq*8);
#pragma unroll
  for (int kt = 0; kt < 16; ++kt) whh0[kt] = loadWfrag(Whh0, NH, cb + lr, kt*32 + lq*8);
#pragma unroll
  for (int kt = 0; kt < 16; ++kt) wih1[kt] = loadWfrag(Wih1, NH, cb + lr, kt*32 + lq*8);
#pragma unroll
  for (int kt = 0; kt < 16; ++kt) whh1[kt] = loadWfrag(Whh1, NH, cb + lr, kt*32 + lq*8);

  const f32x4 bias0 = *(const f32x4*)(bih0 + cb + lq*4) + *(const f32x4*)(bhh0 + cb + lq*4);
  const f32x4 bias1 = *(const f32x4*)(bih1 + cb + lq*4) + *(const f32x4*)(bhh1 + cb + lq*4);

  // ---------------- discovery: is this group single-XCD? ----------------
  const int membq = (g & 7) + 8 * (lane & 7) + 64 * (g >> 3);
  unsigned mv;
  for (;;) {
    mv = ld_u32(xcc + membq);
    if (__all((mv & 0xff00u) == 0x5A00u)) break;
  }
  const bool fastp = __all(mv == (unsigned)__shfl((int)mv, 0, 64));

  unsigned* flg = flags + g * 64;  // 32 used; own 128B line per group
  u64* h0u = (u64*)h0g;
  u64* h1u = (u64*)h1g;

  // ---------------- prologue staging (R4-identical) ----------------
  { // x_0 -> X[0]
    int r = tid >> 4, i0 = (tid & 15) * 8;
    const float4* xp = (const float4*)(x + ((size_t)(row0 + r) * NT + 0) * NI + i0);
    bf16x8 v = cvt8(xp[0], xp[1]);
    int o = r * 256 + i0 * 2;
    *(bf16x8*)(smem + XOFF + (o ^ ((r & 7) << 4))) = v;
  }
#pragma unroll
  for (int it = 0; it < 4; ++it) { // hidden[0]->h0L, hidden[1]->h1L
    int e = it * 2048 + tid * 8;
    int r = e >> 9, c = e & 511;
    int o = r * 1024 + c * 2;
    const float4* hp0 = (const float4*)(hid + (size_t)(row0 + r) * NH + c);
    *(bf16x8*)(smem + H0OFF + (o ^ ((r & 7) << 4))) = cvt8(hp0[0], hp0[1]);
    const float4* hp1 = (const float4*)(hid + (size_t)NB * NH + (size_t)(row0 + r) * NH + c);
    *(bf16x8*)(smem + H1OFF + (o ^ ((r & 7) << 4))) = cvt8(hp1[0], hp1[1]);
  }
  __syncthreads();

#define HFRAG(base, kt) (*(const bf16x8*)((base) + lr * 1024 + (((kt) * 64 + lq * 16) ^ ((lr & 7) << 4))))

  // tick t: compute h0(t) [t<NT] and h1(t-1) [t>0]; one flag+poll+barrier per tick
  for (int t = 0; t <= NT; ++t) {
    const char* xA  = smem + XOFF + (t & 1) * XSZ;
    char* h0L = smem + H0OFF;   // holds h0(t-1)
    char* h1L = smem + H1OFF;   // holds h1(t-2)
    const bool do0 = (t < NT), do1 = (t > 0);
    const size_t sl0 = ((size_t)(t & 1) * NGRP + g) * (RPG * NH);        // h0(t) slab
    const size_t sl1 = ((size_t)((t + 1) & 1) * NGRP + g) * (RPG * NH);  // h1(t-1) slab

    if (do0) {
      f32x4 a0={0.f,0.f,0.f,0.f}, a1={0.f,0.f,0.f,0.f};
#pragma unroll
      for (int kt = 0; kt < 4; ++kt) {
        bf16x8 a = *(const bf16x8*)(xA + lr * 256 + ((kt * 64 + lq * 16) ^ ((lr & 7) << 4)));
        a0 = MFMA16(wih0[kt], a, a0);
      }
#pragma unroll
      for (int kt = 0; kt < 16; ++kt) {
        bf16x8 a = HFRAG(h0L, kt);
        if (kt & 1) a1 = MFMA16(whh0[kt], a, a1); else a0 = MFMA16(whh0[kt], a, a0);
      }
      f32x4 s = a0 + a1 + bias0;
      f32x4 h; h[0]=fast_tanh(s[0]); h[1]=fast_tanh(s[1]); h[2]=fast_tanh(s[2]); h[3]=fast_tanh(s[3]);
      if (t == NT - 1)
        *(f32x4*)(out + NB * NO + (size_t)(row0 + lr) * NH + cb + lq * 4) = h;  // new_hidden[0]
      u64* p = h0u + ((sl0 + (size_t)lr * NH + cb + lq * 4) >> 2);
      u64 pk = pack4bf(h);
      if (fastp) *(volatile u64*)p = pk;  // plain write-through -> shared L2
      else       st_u64(p, pk);
    }

    if (do1) {
      f32x4 c0={0.f,0.f,0.f,0.f}, c1={0.f,0.f,0.f,0.f};
#pragma unroll
      for (int kt = 0; kt < 16; ++kt) {
        bf16x8 a = HFRAG(h0L, kt);   // h0(t-1)
        if (kt & 1) c1 = MFMA16(wih1[kt], a, c1); else c0 = MFMA16(wih1[kt], a, c0);
      }
#pragma unroll
      for (int kt = 0; kt < 16; ++kt) {
        bf16x8 a = HFRAG(h1L, kt);   // h1(t-2)
        if (kt & 1) c1 = MFMA16(whh1[kt], a, c1); else c0 = MFMA16(whh1[kt], a, c0);
      }
      f32x4 s = c0 + c1 + bias1;
      f32x4 h; h[0]=fast_tanh(s[0]); h[1]=fast_tanh(s[1]); h[2]=fast_tanh(s[2]); h[3]=fast_tanh(s[3]);
      if (t == NT)
        *(f32x4*)(out + NB * NO + (size_t)NB * NH + (size_t)(row0 + lr) * NH + cb + lq * 4) = h;  // new_hidden[1]
      u64* p = h1u + ((sl1 + (size_t)lr * NH + cb + lq * 4) >> 2);
      u64 pk = pack4bf(h);
      if (fastp) *(volatile u64*)p = pk;
      else       st_u64(p, pk);
    }

    // prefetch x(t+1) into the inactive x LDS buffer
    if (t + 1 < NT) {
      int r = tid >> 4, i0 = (tid & 15) * 8;
      const float4* xp = (const float4*)(x + ((size_t)(row0 + r) * NT + (t + 1)) * NI + i0);
      bf16x8 v = cvt8(xp[0], xp[1]);
      char* dst = smem + XOFF + ((t + 1) & 1) * XSZ;
      *(bf16x8*)(dst + ((r * 256 + i0 * 2) ^ ((r & 7) << 4))) = v;
    }

    // release-by-drain (publish stores at L2/L3), then PROVEN sc1 flag store
    asm volatile("s_waitcnt vmcnt(0)" ::: "memory");
    if (lane == 0) st_u32(flg + wid, (unsigned)(t + 1));
    if (t == NT) break;

    // PROVEN sc1 poll: one coalesced 128B flag read per iteration (no hang risk)
    {
      const int need = t + 1;
      for (;;) {
        unsigned f = ld_u32(flg + (lane & 31));
        if (__all((int)f - need >= 0)) break;
      }
      asm volatile("" ::: "memory");
    }

    // ingest slabs -> LDS once per block
    u64 v0[8], v1[8];
    if (fastp) {
      l1_inv();  // drop stale L1 lines; plain loads below refill from shared L2
#pragma unroll
      for (int it = 0; it < 8; ++it) v0[it] = *(const volatile u64*)(h0u + (sl0 >> 2) + it * 256 + tid);
      if (do1) {
#pragma unroll
        for (int it = 0; it < 8; ++it) v1[it] = *(const volatile u64*)(h1u + (sl1 >> 2) + it * 256 + tid);
      }
    } else {
#pragma unroll
      for (int it = 0; it < 8; ++it) v0[it] = ld_u64(h0u + (sl0 >> 2) + it * 256 + tid);
      if (do1) {
#pragma unroll
        for (int it = 0; it < 8; ++it) v1[it] = ld_u64(h1u + (sl1 >> 2) + it * 256 + tid);
      }
    }
#pragma unroll
    for (int it = 0; it < 8; ++it) {
      int o = (it * 256 + tid) * 8, r = o >> 10;
      *(u64*)(h0L + (o ^ ((r & 7) << 4))) = v0[it];
    }
    if (do1) {
#pragma unroll
      for (int it = 0; it < 8; ++it) {
        int o = (it * 256 + tid) * 8, r = o >> 10;
        *(u64*)(h1L + (o ^ ((r & 7) << 4))) = v1[it];
      }
    }
    __syncthreads();
  }

  // ---------------- FC epilogue: out = h1(NT-1) @ fcW^T + fcb ----------------
  {
    const int need = NT + 1;
    for (;;) {
      unsigned f = ld_u32(flg + (lane & 31));
      if (__all((int)f - need >= 0)) break;
    }
    asm volatile("" ::: "memory");
  }
  if (wv == 0) {
    const size_t slF = ((size_t)((NT + 1) & 1) * NGRP + g) * (RPG * NH);  // parity of h1(NT-1)
    if (fastp) l1_inv();
    f32x4 acc = {0.f,0.f,0.f,0.f};
#pragma unroll
    for (int kt = 0; kt < 16; ++kt) {
      union { u64 q[2]; bf16x8 v; } un;
      const u64* p = h1u + ((slF + (size_t)lr * NH + kt*32 + lq*8) >> 2);
      if (fastp) { un.q[0] = *(const volatile u64*)p; un.q[1] = *(const volatile u64*)(p + 1); }
      else       { un.q[0] = ld_u64(p);               un.q[1] = ld_u64(p + 1); }
      bf16x8 a = loadWfrag(fcW, NH, j * 16 + lr, kt*32 + lq*8);
      acc = MFMA16(a, un.v, acc);
    }
    f32x4 fb = *(const f32x4*)(fcb + j * 16 + lq * 4);
    *(f32x4*)(out + (size_t)(row0 + lr) * NO + j * 16 + lq * 4) = acc + fb;
  }
#undef HFRAG
}

extern "C" void kernel_launch(void* const* d_in, const int* in_sizes, int n_in,
                              void* d_out, int out_size, void* d_ws, size_t ws_size,
                              hipStream_t stream)
{
  const float* x    = (const float*)d_in[0];
  const float* hid  = (const float*)d_in[1];
  const float* Wih0 = (const float*)d_in[2];
  const float* bih0 = (const float*)d_in[3];
  const float* Whh0 = (const float*)d_in[4];
  const float* bhh0 = (const float*)d_in[5];
  const float* Wih1 = (const float*)d_in[6];
  const float* bih1 = (const float*)d_in[7];
  const float* Whh1 = (const float*)d_in[8];
  const float* bhh1 = (const float*)d_in[9];
  const float* fcW  = (const float*)d_in[10];
  const float* fcb  = (const float*)d_in[11];
  float* out = (float*)d_out;

  unsigned* xcc   = (unsigned*)d_ws;                        // [0, 512)
  unsigned* flags = (unsigned*)((char*)d_ws + 4096);        // [4K, 8K)
  __bf16* h0g = (__bf16*)((char*)d_ws + 65536);             // 512KB
  __bf16* h1g = (__bf16*)((char*)d_ws + 65536 + (size_t)2 * NGRP * RPG * NH * 2);

  // zero XCC slots + tick flags every launch (placement may change per run)
  (void)hipMemsetAsync(d_ws, 0, 16384, stream);

  hipLaunchKernelGGL(rnn_persistent, dim3(NGRP * BPG), dim3(256), 0, stream,
                     x, hid, Wih0, bih0, Whh0, bhh0, Wih1, bih1, Whh1, bhh1,
                     fcW, fcb, out, xcc, flags, h0g, h1g);
}

// Round 7
// 2176.307 us; speedup vs baseline: 2.0613x; 2.0613x over previous
//
#include <hip/hip_runtime.h>

// ---------------- problem constants ----------------
#define NB 256     // batch
#define NT 512     // seq len
#define NI 128     // input size
#define NH 512     // hidden
#define NO 128     // output size
#define NGRP 16    // batch groups
#define RPG 16     // rows (batch) per group
#define BPG 8      // blocks per group (each owns 64 cols)

typedef __attribute__((ext_vector_type(8))) __bf16 bf16x8;
typedef __attribute__((ext_vector_type(4))) float  f32x4;
typedef unsigned long long u64;

#define MFMA16(a,b,c) __builtin_amdgcn_mfma_f32_16x16x32_bf16((a),(b),(c),0,0,0)

// ---------------- LDS layout (R4-identical) ----------------
#define XSZ   (RPG*NI*2)           // 4096
#define HSZ   (RPG*NH*2)           // 16384
#define XOFF  0
#define H0OFF (2*XSZ)              // 8192
#define H1OFF (H0OFF + HSZ)        // 24576
#define SMEM_BYTES (H1OFF + HSZ)   // 40960

// ---------------- exchange slabs (data + checksum tags) ----------------
#define SLABU   2048               // u64 per (layer,parity,group) slab = 16KB
#define TAGBASE 131072             // u64 offset of tag region (= 1 MB)

__device__ __forceinline__ float fast_tanh(float x){
  x = fminf(15.f, fmaxf(-15.f, x));
  float e = __expf(2.f * x);
  return 1.f - 2.f / (e + 1.f);
}

__device__ __forceinline__ bf16x8 cvt8(float4 a, float4 b){
  bf16x8 r;
  r[0]=(__bf16)a.x; r[1]=(__bf16)a.y; r[2]=(__bf16)a.z; r[3]=(__bf16)a.w;
  r[4]=(__bf16)b.x; r[5]=(__bf16)b.y; r[6]=(__bf16)b.z; r[7]=(__bf16)b.w;
  return r;
}

__device__ __forceinline__ bf16x8 loadWfrag(const float* __restrict__ W, int ldk, int row, int k0){
  const float4* p = (const float4*)(W + (size_t)row * ldk + k0);
  return cvt8(p[0], p[1]);
}

// proven medium: relaxed agent-scope atomics (coherent at L3, any placement)
__device__ __forceinline__ void st_u64(u64* p, u64 v){
  __hip_atomic_store(p, v, __ATOMIC_RELAXED, __HIP_MEMORY_SCOPE_AGENT);
}
__device__ __forceinline__ u64 ld_u64(const u64* p){
  return __hip_atomic_load(p, __ATOMIC_RELAXED, __HIP_MEMORY_SCOPE_AGENT);
}

__device__ __forceinline__ u64 pack4bf(f32x4 v){
  union { __bf16 h[4]; u64 u; } un;
  un.h[0]=(__bf16)v[0]; un.h[1]=(__bf16)v[1]; un.h[2]=(__bf16)v[2]; un.h[3]=(__bf16)v[3];
  return un.u;
}

// checksum tag: detects staleness AND tearing; mismatch -> retry
__device__ __forceinline__ unsigned cksum(unsigned tick, u64 d){
  return tick + (unsigned)d + (unsigned)(d >> 32);
}

__device__ __forceinline__ u64* slab(u64* b, int l, int p, int g){
  return b + ((size_t)(((l << 1) | p) * NGRP + g)) * SLABU;
}

__global__ __launch_bounds__(256, 1)
void rnn_persistent(const float* __restrict__ x,
                    const float* __restrict__ hid,
                    const float* __restrict__ Wih0, const float* __restrict__ bih0,
                    const float* __restrict__ Whh0, const float* __restrict__ bhh0,
                    const float* __restrict__ Wih1, const float* __restrict__ bih1,
                    const float* __restrict__ Whh1, const float* __restrict__ bhh1,
                    const float* __restrict__ fcW,  const float* __restrict__ fcb,
                    float* __restrict__ out,
                    u64* __restrict__ ex)           // data slabs; tags at ex+TAGBASE
{
  __shared__ __align__(16) char smem[SMEM_BYTES];

  const int tid  = threadIdx.x;
  const int lane = tid & 63;
  const int wv   = tid >> 6;
  const int lr   = lane & 15;
  const int lq   = lane >> 4;

  const int bq  = blockIdx.x;
  const int j   = (bq >> 3) & 7;            // block-in-group: cols [j*64, j*64+64)
  const int g   = (bq & 7) + 8 * (bq >> 6); // group 0..15
  const int cb  = j * 64 + wv * 16;
  const int row0 = g * RPG;
  const int myq  = j * 16 + wv * 4 + lq;    // this lane's col-quad index 0..127

  u64* const dat = ex;
  u64* const tag = ex + TAGBASE;

  // ---------------- weights -> registers (MFMA A operands) ----------------
  bf16x8 wih0[4], whh0[16], wih1[16], whh1[16];
#pragma unroll
  for (int kt = 0; kt < 4;  ++kt) wih0[kt] = loadWfrag(Wih0, NI, cb + lr, kt*32 + lq*8);
#pragma unroll
  for (int kt = 0; kt < 16; ++kt) whh0[kt] = loadWfrag(Whh0, NH, cb + lr, kt*32 + lq*8);
#pragma unroll
  for (int kt = 0; kt < 16; ++kt) wih1[kt] = loadWfrag(Wih1, NH, cb + lr, kt*32 + lq*8);
#pragma unroll
  for (int kt = 0; kt < 16; ++kt) whh1[kt] = loadWfrag(Whh1, NH, cb + lr, kt*32 + lq*8);

  const f32x4 bias0 = *(const f32x4*)(bih0 + cb + lq*4) + *(const f32x4*)(bhh0 + cb + lq*4);
  const f32x4 bias1 = *(const f32x4*)(bih1 + cb + lq*4) + *(const f32x4*)(bhh1 + cb + lq*4);

  // ---------------- prologue staging ----------------
  { // x_0 -> X[0]
    int r = tid >> 4, i0 = (tid & 15) * 8;
    const float4* xp = (const float4*)(x + ((size_t)(row0 + r) * NT + 0) * NI + i0);
    bf16x8 v = cvt8(xp[0], xp[1]);
    int o = r * 256 + i0 * 2;
    *(bf16x8*)(smem + XOFF + (o ^ ((r & 7) << 4))) = v;
  }
#pragma unroll
  for (int it = 0; it < 4; ++it) { // hidden[0]->h0L, hidden[1]->h1L
    int e = it * 2048 + tid * 8;
    int r = e >> 9, c = e & 511;
    int o = r * 1024 + c * 2;
    const float4* hp0 = (const float4*)(hid + (size_t)(row0 + r) * NH + c);
    *(bf16x8*)(smem + H0OFF + (o ^ ((r & 7) << 4))) = cvt8(hp0[0], hp0[1]);
    const float4* hp1 = (const float4*)(hid + (size_t)NB * NH + (size_t)(row0 + r) * NH + c);
    *(bf16x8*)(smem + H1OFF + (o ^ ((r & 7) << 4))) = cvt8(hp1[0], hp1[1]);
  }
  __syncthreads();

#define HFRAG(base, kt) (*(const bf16x8*)((base) + lr * 1024 + (((kt) * 64 + lq * 16) ^ ((lr & 7) << 4))))

// self-validating ingest: retry this wave's 8 quanta until checksums match tick
#define INGEST(V, D, T, TICK)                                                        \
  for (;;) {                                                                         \
    u64 tg_[8];                                                                      \
    _Pragma("unroll") for (int i_ = 0; i_ < 8; ++i_) V[i_]  = ld_u64((D) + i_*256 + tid); \
    _Pragma("unroll") for (int i_ = 0; i_ < 8; ++i_) tg_[i_] = ld_u64((T) + i_*256 + tid); \
    bool ok_ = true;                                                                 \
    _Pragma("unroll") for (int i_ = 0; i_ < 8; ++i_)                                 \
      ok_ &= ((unsigned)tg_[i_] == cksum((TICK), V[i_]));                            \
    if (ok_) break;                                                                  \
  }

  // tick t: compute h0(t) [t<NT] and h1(t-1) [t>0]
  for (int t = 0; t <= NT; ++t) {
    const char* xA  = smem + XOFF + (t & 1) * XSZ;
    char* h0L = smem + H0OFF;   // holds h0(t-1)
    char* h1L = smem + H1OFF;   // holds h1(t-2)
    const bool do0 = (t < NT), do1 = (t > 0);
    const unsigned tick = (unsigned)(t + 1);

    u64* D0 = slab(dat, 0, t & 1, g);        u64* T0 = slab(tag, 0, t & 1, g);
    u64* D1 = slab(dat, 1, (t + 1) & 1, g);  u64* T1 = slab(tag, 1, (t + 1) & 1, g);

    if (do0) {
      f32x4 a0={0.f,0.f,0.f,0.f}, a1={0.f,0.f,0.f,0.f};
#pragma unroll
      for (int kt = 0; kt < 4; ++kt) {
        bf16x8 a = *(const bf16x8*)(xA + lr * 256 + ((kt * 64 + lq * 16) ^ ((lr & 7) << 4)));
        a0 = MFMA16(wih0[kt], a, a0);
      }
#pragma unroll
      for (int kt = 0; kt < 16; ++kt) {
        bf16x8 a = HFRAG(h0L, kt);
        if (kt & 1) a1 = MFMA16(whh0[kt], a, a1); else a0 = MFMA16(whh0[kt], a, a0);
      }
      f32x4 s = a0 + a1 + bias0;
      f32x4 h; h[0]=fast_tanh(s[0]); h[1]=fast_tanh(s[1]); h[2]=fast_tanh(s[2]); h[3]=fast_tanh(s[3]);
      if (t == NT - 1)
        *(f32x4*)(out + NB * NO + (size_t)(row0 + lr) * NH + cb + lq * 4) = h;  // new_hidden[0]
      u64 d = pack4bf(h);
      int idx = lr * 128 + myq;
      st_u64(D0 + idx, d);
      st_u64(T0 + idx, (u64)cksum(tick, d));
    }

    if (do1) {
      f32x4 c0={0.f,0.f,0.f,0.f}, c1={0.f,0.f,0.f,0.f};
#pragma unroll
      for (int kt = 0; kt < 16; ++kt) {
        bf16x8 a = HFRAG(h0L, kt);   // h0(t-1)
        if (kt & 1) c1 = MFMA16(wih1[kt], a, c1); else c0 = MFMA16(wih1[kt], a, c0);
      }
#pragma unroll
      for (int kt = 0; kt < 16; ++kt) {
        bf16x8 a = HFRAG(h1L, kt);   // h1(t-2)
        if (kt & 1) c1 = MFMA16(whh1[kt], a, c1); else c0 = MFMA16(whh1[kt], a, c0);
      }
      f32x4 s = c0 + c1 + bias1;
      f32x4 h; h[0]=fast_tanh(s[0]); h[1]=fast_tanh(s[1]); h[2]=fast_tanh(s[2]); h[3]=fast_tanh(s[3]);
      if (t == NT)
        *(f32x4*)(out + NB * NO + (size_t)NB * NH + (size_t)(row0 + lr) * NH + cb + lq * 4) = h;  // new_hidden[1]
      u64 d = pack4bf(h);
      int idx = lr * 128 + myq;
      st_u64(D1 + idx, d);
      st_u64(T1 + idx, (u64)cksum(tick, d));
    }
    asm volatile("" ::: "memory");   // publishes issued before ingest loads
    if (t == NT) break;

    // x(t+1) prefetch to registers (in flight during ingest)
    float4 xr0, xr1;
    const bool xpf = (t + 1 < NT);
    if (xpf) {
      int r = tid >> 4, i0 = (tid & 15) * 8;
      const float4* xp = (const float4*)(x + ((size_t)(row0 + r) * NT + (t + 1)) * NI + i0);
      xr0 = xp[0]; xr1 = xp[1];
    }

    // ---- self-validating ingest (no drain, no flags, no poll) ----
    u64 v0[8], v1[8];
    INGEST(v0, D0, T0, tick);
    if (do1) { INGEST(v1, D1, T1, tick); }

    __syncthreads();   // all LDS reads of this tick complete before overwrite
#pragma unroll
    for (int it = 0; it < 8; ++it) {
      int o = (it * 256 + tid) * 8, r = o >> 10;
      *(u64*)(h0L + (o ^ ((r & 7) << 4))) = v0[it];
    }
    if (do1) {
#pragma unroll
      for (int it = 0; it < 8; ++it) {
        int o = (it * 256 + tid) * 8, r = o >> 10;
        *(u64*)(h1L + (o ^ ((r & 7) << 4))) = v1[it];
      }
    }
    if (xpf) {
      int r = tid >> 4, i0 = (tid & 15) * 8;
      bf16x8 v = cvt8(xr0, xr1);
      char* dst = smem + XOFF + ((t + 1) & 1) * XSZ;
      *(bf16x8*)(dst + ((r * 256 + i0 * 2) ^ ((r & 7) << 4))) = v;
    }
    __syncthreads();
  }

  // ---------------- FC epilogue: out = h1(NT-1) @ fcW^T + fcb ----------------
  {
    // h1(NT-1) slab: layer 1, parity (NT+1)&1 = 1, tick NT+1
    u64* DF = slab(dat, 1, 1, g);
    u64* TF = slab(tag, 1, 1, g);
    u64 vf[8];
    INGEST(vf, DF, TF, (unsigned)(NT + 1));
    __syncthreads();
    char* h1L = smem + H1OFF;
#pragma unroll
    for (int it = 0; it < 8; ++it) {
      int o = (it * 256 + tid) * 8, r = o >> 10;
      *(u64*)(h1L + (o ^ ((r & 7) << 4))) = vf[it];
    }
    __syncthreads();
  }
  if (wv == 0) {
    const char* h1L = smem + H1OFF;
    f32x4 acc = {0.f,0.f,0.f,0.f};
#pragma unroll
    for (int kt = 0; kt < 16; ++kt) {
      bf16x8 b = HFRAG(h1L, kt);
      bf16x8 a = loadWfrag(fcW, NH, j * 16 + lr, kt * 32 + lq * 8);
      acc = MFMA16(a, b, acc);
    }
    f32x4 fb = *(const f32x4*)(fcb + j * 16 + lq * 4);
    *(f32x4*)(out + (size_t)(row0 + lr) * NO + j * 16 + lq * 4) = acc + fb;
  }
#undef INGEST
#undef HFRAG
}

extern "C" void kernel_launch(void* const* d_in, const int* in_sizes, int n_in,
                              void* d_out, int out_size, void* d_ws, size_t ws_size,
                              hipStream_t stream)
{
  const float* x    = (const float*)d_in[0];
  const float* hid  = (const float*)d_in[1];
  const float* Wih0 = (const float*)d_in[2];
  const float* bih0 = (const float*)d_in[3];
  const float* Whh0 = (const float*)d_in[4];
  const float* bhh0 = (const float*)d_in[5];
  const float* Wih1 = (const float*)d_in[6];
  const float* bih1 = (const float*)d_in[7];
  const float* Whh1 = (const float*)d_in[8];
  const float* bhh1 = (const float*)d_in[9];
  const float* fcW  = (const float*)d_in[10];
  const float* fcb  = (const float*)d_in[11];
  float* out = (float*)d_out;

  u64* ex = (u64*)d_ws;   // [0,1MB) data slabs, [1MB,2MB) checksum tags

  // zero data+tag slabs every launch (replay safety: no stale tag can validate)
  (void)hipMemsetAsync(d_ws, 0, (size_t)2 * TAGBASE * sizeof(u64) == 0 ? 0 : (size_t)2 * 1024 * 1024, stream);

  hipLaunchKernelGGL(rnn_persistent, dim3(NGRP * BPG), dim3(256), 0, stream,
                     x, hid, Wih0, bih0, Whh0, bhh0, Wih1, bih1, Whh1, bhh1,
                     fcW, fcb, out, ex);
}